// Round 2
// 1053.345 us; speedup vs baseline: 1.4785x; 1.4785x over previous
//
#include <hip/hip_runtime.h>
#include <hip/hip_bf16.h>

#define N_ROWS 100000
#define D 256
#define B 512
#define RT 16          // rows per block in fused kernel (100000 = 6250 * 16)
#define PPAD 516       // p_lds row stride (floats): 512 + 4, multiple of 4 keeps float4 alignment

__device__ __forceinline__ float lo16(unsigned u) { return __uint_as_float(u << 16); }
__device__ __forceinline__ float hi16(unsigned u) { return __uint_as_float(u & 0xffff0000u); }
__device__ __forceinline__ unsigned short bf16r(float f) {
    unsigned u = __float_as_uint(f);
    unsigned r = (u + 0x7fffu + ((u >> 16) & 1u)) >> 16;   // RNE
    return (unsigned short)r;
}

// ---- dtype-generic accessors (BH = inputs/outputs are bf16; else fp32) ----
template<bool BH>
__device__ __forceinline__ float ldf(const void* p, size_t i) {
    if constexpr (BH) return lo16(((const unsigned short*)p)[i]);
    else              return ((const float*)p)[i];
}
template<bool BH>
__device__ __forceinline__ void ld8(const void* p, size_t i, float* o) {  // i multiple of 8
    if constexpr (BH) {
        uint4 v = *(const uint4*)((const unsigned short*)p + i);
        o[0]=lo16(v.x); o[1]=hi16(v.x); o[2]=lo16(v.y); o[3]=hi16(v.y);
        o[4]=lo16(v.z); o[5]=hi16(v.z); o[6]=lo16(v.w); o[7]=hi16(v.w);
    } else {
        const float4* q = (const float4*)((const float*)p + i);
        float4 a = q[0], b = q[1];
        o[0]=a.x; o[1]=a.y; o[2]=a.z; o[3]=a.w;
        o[4]=b.x; o[5]=b.y; o[6]=b.z; o[7]=b.w;
    }
}
template<bool BH>
__device__ __forceinline__ void stf(void* p, size_t i, float v) {
    if constexpr (BH) ((unsigned short*)p)[i] = bf16r(v);
    else              ((float*)p)[i] = v;
}

// ---------------- Kernel 0: dtype sniff ----------------
// fp32 N(0,1): low 16 bits of each word are uniform mantissa bits -> as-bf16
// exponent > 135 with p=0.47 per word; 128 words => P(all pass) ~ 1e-35.
// bf16 N(0,1): every half has exponent <= ~130 -> always passes.
__global__ void sniff_kernel(const unsigned* __restrict__ h, int* __restrict__ flag) {
    if (threadIdx.x == 0 && blockIdx.x == 0) {
        int bad = 0;
        for (int i = 0; i < 128; ++i) {
            unsigned w = h[i];
            unsigned e0 = (w >> 7)  & 0xffu;
            unsigned e1 = (w >> 23) & 0xffu;
            if (e0 > 135u || e1 > 135u) bad = 1;
        }
        *flag = bad ? 0 : 1;   // 1 = bf16
    }
}

// ---------------- Kernel 1: segment sums (scatter atomics) ----------------
template<bool BH>
__device__ __forceinline__ void seg_body(const void* __restrict__ V, const void* __restrict__ bkp,
                                         float* __restrict__ sums, float* __restrict__ counts,
                                         float* __restrict__ gsum) {
    // index-dtype sniff: int64 vs int32 (deterministic, same answer every block)
    bool is64 = true;
    const long long* b64 = (const long long*)bkp;
    #pragma unroll
    for (int j = 0; j < 16; ++j) {
        long long v = b64[j];
        if (v < 0 || v >= B) is64 = false;
    }
    const int* b32 = (const int*)bkp;
    const int t = threadIdx.x;
    float g = 0.f;
    for (int row = blockIdx.x; row < N_ROWS; row += gridDim.x) {
        int k = is64 ? (int)b64[row] : b32[row];
        float v = ldf<BH>(V, (size_t)row * D + t);
        atomicAdd(&sums[k * D + t], v);
        g += v;
        if (t == 0) atomicAdd(&counts[k], 1.0f);
    }
    atomicAdd(&gsum[t], g);
}
__global__ __launch_bounds__(256) void seg_kernel(const void* V, const void* bk,
                                                  float* sums, float* counts, float* gsum,
                                                  const int* flag) {
    if (*flag) seg_body<true>(V, bk, sums, counts, gsum);
    else       seg_body<false>(V, bk, sums, counts, gsum);
}

// ------- Kernel 2: prototypes + protoW = proto @ W_r^T (interleaved f4 layout) -------
template<bool BH>
__device__ __forceinline__ void proto_body(const float* __restrict__ sums,
                                           const float* __restrict__ counts,
                                           const float* __restrict__ gsum,
                                           const void* __restrict__ W_r,
                                           float* __restrict__ protoWi,
                                           float* __restrict__ proto) {
    const int b = blockIdx.x, t = threadIdx.x;
    float c = counts[b];
    proto[t] = (c > 0.5f) ? sums[b * D + t] / c : gsum[t] * (1.0f / N_ROWS);
    __syncthreads();
    // protoW[b][t] = sum_k proto[k] * W_r[t][k]
    float acc = 0.f;
    float w[8];
    #pragma unroll
    for (int c8 = 0; c8 < D / 8; ++c8) {
        ld8<BH>(W_r, (size_t)t * D + c8 * 8, w);
        #pragma unroll
        for (int j = 0; j < 8; ++j) acc = fmaf(proto[c8 * 8 + j], w[j], acc);
    }
    // interleaved: protoWi[(b/4)*1024 + t*4 + (b%4)] -> fused reads float4 per 4-bucket chunk
    protoWi[(size_t)(b >> 2) * (D * 4) + t * 4 + (b & 3)] = acc;
}
__global__ __launch_bounds__(256) void proto_kernel(const float* sums, const float* counts,
                                                    const float* gsum, const void* W_r,
                                                    float* protoWi, const int* flag) {
    __shared__ __align__(16) float proto[D];   // declared ONCE here (no per-instantiation dup)
    if (*flag) proto_body<true>(sums, counts, gsum, W_r, protoWi, proto);
    else       proto_body<false>(sums, counts, gsum, W_r, protoWi, proto);
}

// ------- Kernel 3: softmax+entropy -> matvec -> gated add -> LayerNorm -------
template<bool BH>
__device__ __forceinline__ void fused_body(const void* __restrict__ logits,
                                           const void* __restrict__ h_fused,
                                           const float* __restrict__ protoWi,
                                           const void* __restrict__ gamma,
                                           const void* __restrict__ beta,
                                           void* __restrict__ out,
                                           float* __restrict__ p_lds,
                                           float* __restrict__ part1,
                                           float* __restrict__ part2,
                                           float* __restrict__ gate_lds) {
    const int t = threadIdx.x;
    const long long base_row = (long long)blockIdx.x * RT;

    // ---- phase 1: softmax + entropy for RT rows, 16 threads per row (all 256 active) ----
    {
        const int grp = t >> 4, sub = t & 15;
        const long long row = base_row + grp;
        float x[32];
        #pragma unroll
        for (int c = 0; c < 4; ++c)
            ld8<BH>(logits, (size_t)row * B + sub * 32 + c * 8, &x[c * 8]);
        float m = x[0];
        #pragma unroll
        for (int k = 1; k < 32; ++k) m = fmaxf(m, x[k]);
        m = fmaxf(m, __shfl_xor(m, 1));
        m = fmaxf(m, __shfl_xor(m, 2));
        m = fmaxf(m, __shfl_xor(m, 4));
        m = fmaxf(m, __shfl_xor(m, 8));
        float S = 0.f;
        #pragma unroll
        for (int k = 0; k < 32; ++k) { x[k] = __expf(x[k] - m); S += x[k]; }
        S += __shfl_xor(S, 1); S += __shfl_xor(S, 2); S += __shfl_xor(S, 4); S += __shfl_xor(S, 8);
        const float inv = 1.0f / S;
        float ent = 0.f;
        #pragma unroll
        for (int k = 0; k < 32; ++k) {
            float p = x[k] * inv;
            ent = fmaf(p, __logf(p + 1e-9f), ent);   // sum p*log(p+1e-9) (negative)
            x[k] = p;
        }
        ent += __shfl_xor(ent, 1); ent += __shfl_xor(ent, 2);
        ent += __shfl_xor(ent, 4); ent += __shfl_xor(ent, 8);
        const float gate = -ent * 0.16035674514745464f;  // entropy / ln(512)
        float* prow = &p_lds[grp * PPAD + sub * 32];
        #pragma unroll
        for (int c = 0; c < 8; ++c)
            *(float4*)&prow[c * 4] = make_float4(x[c*4+0], x[c*4+1], x[c*4+2], x[c*4+3]);
        if (sub == 0) {
            gate_lds[grp] = gate;
            stf<BH>(out, (size_t)N_ROWS * D + row, 1.0f - gate);   // confidence
        }
    }
    __syncthreads();

    // ---- phase 2: residual[r][t] = sum_b p[r][b] * protoW[b][t] (fp32 VALU, exact) ----
    float acc[RT];
    #pragma unroll
    for (int r = 0; r < RT; ++r) acc[r] = 0.f;
    const float4* pw4 = (const float4*)protoWi;
    for (int c = 0; c < B / 4; ++c) {
        const float4 w = pw4[c * D + t];   // protoW[4c..4c+3][t], coalesced
        #pragma unroll
        for (int r = 0; r < RT; ++r) {
            const float4 pv = *(const float4*)&p_lds[r * PPAD + c * 4];  // broadcast
            acc[r] = fmaf(pv.x, w.x, acc[r]);
            acc[r] = fmaf(pv.y, w.y, acc[r]);
            acc[r] = fmaf(pv.z, w.z, acc[r]);
            acc[r] = fmaf(pv.w, w.w, acc[r]);
        }
    }

    // ---- phase 3: gated add + LayerNorm ----
    const float g  = ldf<BH>(gamma, t);
    const float bt = ldf<BH>(beta, t);
    const int wv = t >> 6, ln = t & 63;
    #pragma unroll
    for (int r = 0; r < RT; ++r) {
        const long long row = base_row + r;
        float hv = fmaf(gate_lds[r], acc[r], ldf<BH>(h_fused, (size_t)row * D + t));
        acc[r] = hv;
        float s1 = hv, s2 = hv * hv;
        #pragma unroll
        for (int o = 32; o > 0; o >>= 1) { s1 += __shfl_xor(s1, o); s2 += __shfl_xor(s2, o); }
        if (ln == 0) { part1[r * 4 + wv] = s1; part2[r * 4 + wv] = s2; }
    }
    __syncthreads();
    #pragma unroll
    for (int r = 0; r < RT; ++r) {
        float sum = part1[r * 4 + 0] + part1[r * 4 + 1] + part1[r * 4 + 2] + part1[r * 4 + 3];
        float sq  = part2[r * 4 + 0] + part2[r * 4 + 1] + part2[r * 4 + 2] + part2[r * 4 + 3];
        float mean = sum * (1.0f / D);
        float var  = fmaf(-mean, mean, sq * (1.0f / D));
        float rstd = rsqrtf(var + 1e-5f);
        const long long row = base_row + r;
        stf<BH>(out, (size_t)row * D + t, fmaf((acc[r] - mean) * rstd, g, bt));
    }
}
__global__ __launch_bounds__(256, 4) void fused_kernel(const void* logits, const void* h_fused,
                                                       const float* protoWi, const void* gamma,
                                                       const void* beta, void* out, const int* flag) {
    // Single shared allocation in the wrapper: both BH instantiations share it.
    // RT*PPAD + 4*RT + 4*RT + RT = 8256 + 64 + 64 + 16 = 8400 floats = 33600 B -> 4 blocks/CU.
    __shared__ __align__(16) float sm[RT * PPAD + RT * 4 * 2 + RT];
    float* p_lds    = sm;
    float* part1    = sm + RT * PPAD;
    float* part2    = part1 + RT * 4;
    float* gate_lds = part2 + RT * 4;
    if (*flag) fused_body<true>(logits, h_fused, protoWi, gamma, beta, out,
                                p_lds, part1, part2, gate_lds);
    else       fused_body<false>(logits, h_fused, protoWi, gamma, beta, out,
                                 p_lds, part1, part2, gate_lds);
}

extern "C" void kernel_launch(void* const* d_in, const int* in_sizes, int n_in,
                              void* d_out, int out_size, void* d_ws, size_t ws_size,
                              hipStream_t stream) {
    const void* h_fused = d_in[0];
    const void* V       = d_in[1];
    const void* logits  = d_in[2];
    const void* bk      = d_in[3];
    const void* W_r     = d_in[4];
    const void* gamma   = d_in[5];
    const void* beta    = d_in[6];

    float* ws      = (float*)d_ws;
    float* sums    = ws;                 // B*D   = 131072 f32
    float* counts  = ws + 131072;        // B     = 512
    float* gsum    = ws + 131584;        // D     = 256
    float* protoWi = ws + 131840;        // B*D   = 131072 (16B-aligned)
    int*   flag    = (int*)(ws + 262912);

    hipMemsetAsync(d_ws, 0, (size_t)131840 * sizeof(float), stream);
    sniff_kernel<<<1, 64, 0, stream>>>((const unsigned*)h_fused, flag);
    seg_kernel<<<1024, 256, 0, stream>>>(V, bk, sums, counts, gsum, flag);
    proto_kernel<<<B, 256, 0, stream>>>(sums, counts, gsum, W_r, protoWi, flag);
    fused_kernel<<<N_ROWS / RT, 256, 0, stream>>>(logits, h_fused, protoWi, gamma, beta, d_out, flag);
}

// Round 3
// 668.947 us; speedup vs baseline: 2.3281x; 1.5746x over previous
//
#include <hip/hip_runtime.h>
#include <hip/hip_bf16.h>

#define N_ROWS 100000
#define D 256
#define B 512
#define RT 16          // rows per block in fused kernel (100000 = 6250 * 16)
#define RS 260         // residual LDS row stride (floats): 256 + 4

typedef __attribute__((ext_vector_type(8))) short sh8;     // 8 bf16 = 4 VGPRs (MFMA A/B frag)
typedef __attribute__((ext_vector_type(4))) float f32x4;   // MFMA C/D frag

__device__ __forceinline__ float lo16(unsigned u) { return __uint_as_float(u << 16); }
__device__ __forceinline__ float hi16(unsigned u) { return __uint_as_float(u & 0xffff0000u); }
__device__ __forceinline__ unsigned short bf16r(float f) {
    unsigned u = __float_as_uint(f);
    unsigned r = (u + 0x7fffu + ((u >> 16) & 1u)) >> 16;   // RNE
    return (unsigned short)r;
}

// ---- dtype-generic accessors (BH = inputs/outputs are bf16; else fp32) ----
template<bool BH>
__device__ __forceinline__ float ldf(const void* p, size_t i) {
    if constexpr (BH) return lo16(((const unsigned short*)p)[i]);
    else              return ((const float*)p)[i];
}
template<bool BH>
__device__ __forceinline__ void ld8(const void* p, size_t i, float* o) {  // i multiple of 8
    if constexpr (BH) {
        uint4 v = *(const uint4*)((const unsigned short*)p + i);
        o[0]=lo16(v.x); o[1]=hi16(v.x); o[2]=lo16(v.y); o[3]=hi16(v.y);
        o[4]=lo16(v.z); o[5]=hi16(v.z); o[6]=lo16(v.w); o[7]=hi16(v.w);
    } else {
        const float4* q = (const float4*)((const float*)p + i);
        float4 a = q[0], b = q[1];
        o[0]=a.x; o[1]=a.y; o[2]=a.z; o[3]=a.w;
        o[4]=b.x; o[5]=b.y; o[6]=b.z; o[7]=b.w;
    }
}
template<bool BH>
__device__ __forceinline__ void stf(void* p, size_t i, float v) {
    if constexpr (BH) ((unsigned short*)p)[i] = bf16r(v);
    else              ((float*)p)[i] = v;
}

// ---------------- Kernel 0: dtype sniff ----------------
// fp32 N(0,1): low 16 bits of each word are uniform mantissa bits -> as-bf16
// exponent > 135 with p=0.47 per word; 128 words => P(all pass) ~ 1e-35.
// bf16 N(0,1): every half has exponent <= ~130 -> always passes.
__global__ void sniff_kernel(const unsigned* __restrict__ h, int* __restrict__ flag) {
    if (threadIdx.x == 0 && blockIdx.x == 0) {
        int bad = 0;
        for (int i = 0; i < 128; ++i) {
            unsigned w = h[i];
            unsigned e0 = (w >> 7)  & 0xffu;
            unsigned e1 = (w >> 23) & 0xffu;
            if (e0 > 135u || e1 > 135u) bad = 1;
        }
        *flag = bad ? 0 : 1;   // 1 = bf16
    }
}

// ---------------- Kernel 1: segment sums (scatter atomics) ----------------
template<bool BH>
__device__ __forceinline__ void seg_body(const void* __restrict__ V, const void* __restrict__ bkp,
                                         float* __restrict__ sums, float* __restrict__ counts,
                                         float* __restrict__ gsum) {
    // index-dtype sniff: int64 vs int32 (deterministic, same answer every block)
    bool is64 = true;
    const long long* b64 = (const long long*)bkp;
    #pragma unroll
    for (int j = 0; j < 16; ++j) {
        long long v = b64[j];
        if (v < 0 || v >= B) is64 = false;
    }
    const int* b32 = (const int*)bkp;
    const int t = threadIdx.x;
    float g = 0.f;
    for (int row = blockIdx.x; row < N_ROWS; row += gridDim.x) {
        int k = is64 ? (int)b64[row] : b32[row];
        float v = ldf<BH>(V, (size_t)row * D + t);
        atomicAdd(&sums[k * D + t], v);
        g += v;
        if (t == 0) atomicAdd(&counts[k], 1.0f);
    }
    atomicAdd(&gsum[t], g);
}
__global__ __launch_bounds__(256) void seg_kernel(const void* V, const void* bk,
                                                  float* sums, float* counts, float* gsum,
                                                  const int* flag) {
    if (*flag) seg_body<true>(V, bk, sums, counts, gsum);
    else       seg_body<false>(V, bk, sums, counts, gsum);
}

// ------- Kernel 2: prototypes + protoW = proto @ W_r^T, emitted as bf16 in ---
// ------- MFMA B-fragment layout: pwB[((b>>3)*256 + col)*8 + (b&7)], b = k-dim ---
template<bool BH>
__device__ __forceinline__ void proto_body(const float* __restrict__ sums,
                                           const float* __restrict__ counts,
                                           const float* __restrict__ gsum,
                                           const void* __restrict__ W_r,
                                           unsigned short* __restrict__ pwB,
                                           float* __restrict__ proto) {
    const int b = blockIdx.x, t = threadIdx.x;
    float c = counts[b];
    proto[t] = (c > 0.5f) ? sums[b * D + t] / c : gsum[t] * (1.0f / N_ROWS);
    __syncthreads();
    // protoW[b][t] = sum_k proto[k] * W_r[t][k]
    float acc = 0.f;
    float w[8];
    #pragma unroll
    for (int c8 = 0; c8 < D / 8; ++c8) {
        ld8<BH>(W_r, (size_t)t * D + c8 * 8, w);
        #pragma unroll
        for (int j = 0; j < 8; ++j) acc = fmaf(proto[c8 * 8 + j], w[j], acc);
    }
    pwB[((size_t)(b >> 3) * 256 + t) * 8 + (b & 7)] = bf16r(acc);
}
__global__ __launch_bounds__(256) void proto_kernel(const float* sums, const float* counts,
                                                    const float* gsum, const void* W_r,
                                                    unsigned short* pwB, const int* flag) {
    __shared__ __align__(16) float proto[D];   // declared ONCE here (no per-instantiation dup)
    if (*flag) proto_body<true>(sums, counts, gsum, W_r, pwB, proto);
    else       proto_body<false>(sums, counts, gsum, W_r, pwB, proto);
}

// ------- Kernel 3: softmax+entropy -> bf16 MFMA matmul -> gated add -> LayerNorm -------
// smu is a union: phase 1/2 use it as the bf16 A tile [64 kgrp][16 row][8] (16384 B);
// after a barrier the phase-2 epilogue reuses it as fp32 residual [16][RS] (16640 B).
template<bool BH>
__device__ __forceinline__ void fused_body(const void* __restrict__ logits,
                                           const void* __restrict__ h_fused,
                                           const unsigned short* __restrict__ pwB,
                                           const void* __restrict__ gamma,
                                           const void* __restrict__ beta,
                                           void* __restrict__ out,
                                           float* __restrict__ smu,
                                           float* __restrict__ part1,
                                           float* __restrict__ part2,
                                           float* __restrict__ gate_lds) {
    const int t = threadIdx.x;
    const long long base_row = (long long)blockIdx.x * RT;

    // ---- phase 1: softmax + entropy for RT rows, 16 threads per row (verbatim round 2,
    //      except p is stored as bf16 in MFMA A-fragment layout instead of fp32) ----
    {
        const int grp = t >> 4, sub = t & 15;
        const long long row = base_row + grp;
        float x[32];
        #pragma unroll
        for (int c = 0; c < 4; ++c)
            ld8<BH>(logits, (size_t)row * B + sub * 32 + c * 8, &x[c * 8]);
        float m = x[0];
        #pragma unroll
        for (int k = 1; k < 32; ++k) m = fmaxf(m, x[k]);
        m = fmaxf(m, __shfl_xor(m, 1));
        m = fmaxf(m, __shfl_xor(m, 2));
        m = fmaxf(m, __shfl_xor(m, 4));
        m = fmaxf(m, __shfl_xor(m, 8));
        float S = 0.f;
        #pragma unroll
        for (int k = 0; k < 32; ++k) { x[k] = __expf(x[k] - m); S += x[k]; }
        S += __shfl_xor(S, 1); S += __shfl_xor(S, 2); S += __shfl_xor(S, 4); S += __shfl_xor(S, 8);
        const float inv = 1.0f / S;
        float ent = 0.f;
        #pragma unroll
        for (int k = 0; k < 32; ++k) {
            float p = x[k] * inv;
            ent = fmaf(p, __logf(p + 1e-9f), ent);   // sum p*log(p+1e-9) (negative)
            x[k] = p;
        }
        ent += __shfl_xor(ent, 1); ent += __shfl_xor(ent, 2);
        ent += __shfl_xor(ent, 4); ent += __shfl_xor(ent, 8);
        const float gate = -ent * 0.16035674514745464f;  // entropy / ln(512)
        // A-tile write: k = sub*32 + c*8 + j  ->  chunk kg = sub*4 + c, row = grp
        unsigned short* A16 = (unsigned short*)smu;
        #pragma unroll
        for (int c = 0; c < 4; ++c) {
            unsigned q0 = (unsigned)bf16r(x[c*8+0]) | ((unsigned)bf16r(x[c*8+1]) << 16);
            unsigned q1 = (unsigned)bf16r(x[c*8+2]) | ((unsigned)bf16r(x[c*8+3]) << 16);
            unsigned q2 = (unsigned)bf16r(x[c*8+4]) | ((unsigned)bf16r(x[c*8+5]) << 16);
            unsigned q3 = (unsigned)bf16r(x[c*8+6]) | ((unsigned)bf16r(x[c*8+7]) << 16);
            *(uint4*)&A16[((size_t)(sub * 4 + c) * 16 + grp) * 8] = make_uint4(q0, q1, q2, q3);
        }
        if (sub == 0) {
            gate_lds[grp] = gate;
            stf<BH>(out, (size_t)N_ROWS * D + row, 1.0f - gate);   // confidence
        }
    }
    __syncthreads();

    // ---- phase 2: residual[16][256] = P[16x512] @ PW[512x256] via bf16 MFMA ----
    // wave w owns cols [w*64, w*64+64): 4 N-tiles x 16 K-steps, single M-tile (M=16)
    {
        const int l  = t & 63, w = t >> 6;
        const int lr = l & 15, lg = l >> 4;
        f32x4 acc[4];
        const f32x4 fz = {0.f, 0.f, 0.f, 0.f};
        #pragma unroll
        for (int n = 0; n < 4; ++n) acc[n] = fz;
        const uint4* Ap = (const uint4*)smu;    // 16B chunk index = kg*16 + row
        const uint4* Bp = (const uint4*)pwB;    // 16B chunk index = kg*256 + col
        #pragma unroll 2
        for (int ks = 0; ks < 16; ++ks) {       // K = 32 per step
            const int kg = ks * 4 + lg;         // lane's k-offset inside step = lg*8 + j
            sh8 a = __builtin_bit_cast(sh8, Ap[kg * 16 + lr]);        // A[row=lr][k=kg*8..+8]
            #pragma unroll
            for (int n = 0; n < 4; ++n) {
                sh8 b = __builtin_bit_cast(sh8, Bp[(size_t)kg * 256 + w * 64 + n * 16 + lr]);
                acc[n] = __builtin_amdgcn_mfma_f32_16x16x32_bf16(a, b, acc[n], 0, 0, 0);
            }
        }
        __syncthreads();                         // all waves done reading A -> reuse smu
        float* res = smu;                        // [16][RS]
        #pragma unroll
        for (int n = 0; n < 4; ++n)
            #pragma unroll
            for (int r = 0; r < 4; ++r)          // C/D: row = (l>>4)*4 + r, col = l&15 (m89)
                res[(lg * 4 + r) * RS + (w * 64 + n * 16 + lr)] = acc[n][r];
    }
    __syncthreads();

    // ---- phase 3: gated add + LayerNorm (verbatim round 2; residual now read from LDS) ----
    {
        const float* res = smu;
        const float g  = ldf<BH>(gamma, t);
        const float bt = ldf<BH>(beta, t);
        const int wv = t >> 6, ln = t & 63;
        float hr[RT];
        #pragma unroll
        for (int r = 0; r < RT; ++r) {
            const long long row = base_row + r;
            float hv = fmaf(gate_lds[r], res[r * RS + t], ldf<BH>(h_fused, (size_t)row * D + t));
            hr[r] = hv;
            float s1 = hv, s2 = hv * hv;
            #pragma unroll
            for (int o = 32; o > 0; o >>= 1) { s1 += __shfl_xor(s1, o); s2 += __shfl_xor(s2, o); }
            if (ln == 0) { part1[r * 4 + wv] = s1; part2[r * 4 + wv] = s2; }
        }
        __syncthreads();
        #pragma unroll
        for (int r = 0; r < RT; ++r) {
            float sum = part1[r * 4 + 0] + part1[r * 4 + 1] + part1[r * 4 + 2] + part1[r * 4 + 3];
            float sq  = part2[r * 4 + 0] + part2[r * 4 + 1] + part2[r * 4 + 2] + part2[r * 4 + 3];
            float mean = sum * (1.0f / D);
            float var  = fmaf(-mean, mean, sq * (1.0f / D));
            float rstd = rsqrtf(var + 1e-5f);
            const long long row = base_row + r;
            stf<BH>(out, (size_t)row * D + t, fmaf((hr[r] - mean) * rstd, g, bt));
        }
    }
}
__global__ __launch_bounds__(256, 4) void fused_kernel(const void* logits, const void* h_fused,
                                                       const unsigned short* pwB, const void* gamma,
                                                       const void* beta, void* out, const int* flag) {
    // Single shared allocation in the wrapper: both BH instantiations share it.
    // union(A16 16384 B, res 16640 B) + part1/part2/gate = 4160+64+64+16 floats = 17216 B
    // -> 8 blocks/CU (wave-limited), up from 4.
    __shared__ __align__(16) float sm[RT * RS + RT * 4 * 2 + RT];
    float* smu      = sm;
    float* part1    = sm + RT * RS;
    float* part2    = part1 + RT * 4;
    float* gate_lds = part2 + RT * 4;
    if (*flag) fused_body<true>(logits, h_fused, pwB, gamma, beta, out,
                                smu, part1, part2, gate_lds);
    else       fused_body<false>(logits, h_fused, pwB, gamma, beta, out,
                                 smu, part1, part2, gate_lds);
}

extern "C" void kernel_launch(void* const* d_in, const int* in_sizes, int n_in,
                              void* d_out, int out_size, void* d_ws, size_t ws_size,
                              hipStream_t stream) {
    const void* h_fused = d_in[0];
    const void* V       = d_in[1];
    const void* logits  = d_in[2];
    const void* bk      = d_in[3];
    const void* W_r     = d_in[4];
    const void* gamma   = d_in[5];
    const void* beta    = d_in[6];

    float* ws      = (float*)d_ws;
    float* sums    = ws;                                   // B*D = 131072 f32
    float* counts  = ws + 131072;                          // B   = 512
    float* gsum    = ws + 131584;                          // D   = 256
    unsigned short* pwB = (unsigned short*)(ws + 131840);  // B*D bf16 = 262144 B (16B-aligned)
    int*   flag    = (int*)(ws + 131840 + 65536);

    hipMemsetAsync(d_ws, 0, (size_t)131840 * sizeof(float), stream);
    sniff_kernel<<<1, 64, 0, stream>>>((const unsigned*)h_fused, flag);
    seg_kernel<<<1024, 256, 0, stream>>>(V, bk, sums, counts, gsum, flag);
    proto_kernel<<<B, 256, 0, stream>>>(sums, counts, gsum, W_r, pwB, flag);
    fused_kernel<<<N_ROWS / RT, 256, 0, stream>>>(logits, h_fused, pwB, gamma, beta, d_out, flag);
}

// Round 4
// 630.865 us; speedup vs baseline: 2.4686x; 1.0604x over previous
//
#include <hip/hip_runtime.h>
#include <hip/hip_bf16.h>

#define N_ROWS 100000
#define D 256
#define B 512
#define RT 16          // rows per block in fused kernel (100000 = 6250 * 16)
#define RS 260         // residual LDS row stride (floats): 256 + 4

typedef __attribute__((ext_vector_type(8))) short sh8;     // 8 bf16 = 4 VGPRs (MFMA A/B frag)
typedef __attribute__((ext_vector_type(4))) float f32x4;   // MFMA C/D frag

__device__ __forceinline__ float lo16(unsigned u) { return __uint_as_float(u << 16); }
__device__ __forceinline__ float hi16(unsigned u) { return __uint_as_float(u & 0xffff0000u); }
__device__ __forceinline__ unsigned short bf16r(float f) {
    unsigned u = __float_as_uint(f);
    unsigned r = (u + 0x7fffu + ((u >> 16) & 1u)) >> 16;   // RNE
    return (unsigned short)r;
}

// ---- dtype-generic accessors (BH = inputs/outputs are bf16; else fp32) ----
template<bool BH>
__device__ __forceinline__ float ldf(const void* p, size_t i) {
    if constexpr (BH) return lo16(((const unsigned short*)p)[i]);
    else              return ((const float*)p)[i];
}
template<bool BH>
__device__ __forceinline__ void ld8(const void* p, size_t i, float* o) {  // i multiple of 8
    if constexpr (BH) {
        uint4 v = *(const uint4*)((const unsigned short*)p + i);
        o[0]=lo16(v.x); o[1]=hi16(v.x); o[2]=lo16(v.y); o[3]=hi16(v.y);
        o[4]=lo16(v.z); o[5]=hi16(v.z); o[6]=lo16(v.w); o[7]=hi16(v.w);
    } else {
        const float4* q = (const float4*)((const float*)p + i);
        float4 a = q[0], b = q[1];
        o[0]=a.x; o[1]=a.y; o[2]=a.z; o[3]=a.w;
        o[4]=b.x; o[5]=b.y; o[6]=b.z; o[7]=b.w;
    }
}
template<bool BH>
__device__ __forceinline__ void stf(void* p, size_t i, float v) {
    if constexpr (BH) ((unsigned short*)p)[i] = bf16r(v);
    else              ((float*)p)[i] = v;
}

// ---- bucket-index dtype sniff (int64 vs int32), deterministic per call ----
__device__ __forceinline__ bool bk_is64(const void* bkp) {
    bool is64 = true;
    const long long* b64 = (const long long*)bkp;
    #pragma unroll
    for (int j = 0; j < 16; ++j) {
        long long v = b64[j];
        if (v < 0 || v >= B) is64 = false;
    }
    return is64;
}

// ---------------- Kernel 0: dtype sniff ----------------
// fp32 N(0,1): low 16 bits of each word are uniform mantissa bits -> as-bf16
// exponent > 135 with p=0.47 per word; 128 words => P(all pass) ~ 1e-35.
__global__ void sniff_kernel(const unsigned* __restrict__ h, int* __restrict__ flag) {
    if (threadIdx.x == 0 && blockIdx.x == 0) {
        int bad = 0;
        for (int i = 0; i < 128; ++i) {
            unsigned w = h[i];
            unsigned e0 = (w >> 7)  & 0xffu;
            unsigned e1 = (w >> 23) & 0xffu;
            if (e0 > 135u || e1 > 135u) bad = 1;
        }
        *flag = bad ? 0 : 1;   // 1 = bf16
    }
}

// ---------------- Kernel 1a: histogram (counts as f32, exact up to 2^24) ----------------
__global__ __launch_bounds__(256) void hist_kernel(const void* __restrict__ bkp,
                                                   float* __restrict__ counts) {
    const bool is64 = bk_is64(bkp);
    const long long* b64 = (const long long*)bkp;
    const int* b32 = (const int*)bkp;
    const int stride = gridDim.x * 256;
    for (int row = blockIdx.x * 256 + threadIdx.x; row < N_ROWS; row += stride) {
        int k = is64 ? (int)b64[row] : b32[row];
        atomicAdd(&counts[k], 1.0f);
    }
}

// ---------------- Kernel 1b: exclusive prefix sum over 512 counts ----------------
__global__ __launch_bounds__(512) void scan_kernel(const float* __restrict__ counts,
                                                   int* __restrict__ offsets,
                                                   int* __restrict__ cursor) {
    __shared__ int lds[B];
    const int t = threadIdx.x;
    const int c = (int)counts[t];
    lds[t] = c;
    __syncthreads();
    #pragma unroll
    for (int off = 1; off < B; off <<= 1) {
        int v = (t >= off) ? lds[t - off] : 0;
        __syncthreads();
        lds[t] += v;
        __syncthreads();
    }
    const int excl = lds[t] - c;
    offsets[t] = excl;
    cursor[t]  = excl;
}

// ---------------- Kernel 1c: scatter row ids into bucket-sorted order ----------------
__global__ __launch_bounds__(256) void scatter_kernel(const void* __restrict__ bkp,
                                                      int* __restrict__ cursor,
                                                      int* __restrict__ order) {
    const bool is64 = bk_is64(bkp);
    const long long* b64 = (const long long*)bkp;
    const int* b32 = (const int*)bkp;
    const int stride = gridDim.x * 256;
    for (int row = blockIdx.x * 256 + threadIdx.x; row < N_ROWS; row += stride) {
        int k = is64 ? (int)b64[row] : b32[row];
        int pos = atomicAdd(&cursor[k], 1);
        order[pos] = row;
    }
}

// ---- Kernel 1d: per-bucket gather-reduce. Block b exclusively owns bucket b:
// ---- sums[b][*] written directly (NO atomics); gsum accumulated as sum of bucket sums.
template<bool BH>
__device__ __forceinline__ void gather_body(const void* __restrict__ V,
                                            const int* __restrict__ order,
                                            const int* __restrict__ offsets,
                                            const float* __restrict__ counts,
                                            float* __restrict__ sums,
                                            float* __restrict__ gsum,
                                            float* __restrict__ red) {
    const int b = blockIdx.x;
    const int start = offsets[b];
    const int cnt = (int)counts[b];
    const int col = threadIdx.x & (D - 1);
    const int half = threadIdx.x >> 8;          // 0 or 1: two row-lanes
    float acc = 0.f;
    int i = half;
    for (; i + 6 < cnt; i += 8) {               // unroll 4 (stride 2 per lane)
        const int r0 = order[start + i];
        const int r1 = order[start + i + 2];
        const int r2 = order[start + i + 4];
        const int r3 = order[start + i + 6];
        const float v0 = ldf<BH>(V, (size_t)r0 * D + col);
        const float v1 = ldf<BH>(V, (size_t)r1 * D + col);
        const float v2 = ldf<BH>(V, (size_t)r2 * D + col);
        const float v3 = ldf<BH>(V, (size_t)r3 * D + col);
        acc += (v0 + v1) + (v2 + v3);
    }
    for (; i < cnt; i += 2)
        acc += ldf<BH>(V, (size_t)order[start + i] * D + col);
    if (half == 1) red[col] = acc;
    __syncthreads();
    if (half == 0) {
        const float tot = acc + red[col];
        sums[(size_t)b * D + col] = tot;
        atomicAdd(&gsum[col], tot);             // gsum = sum over all buckets = global V sum
    }
}
__global__ __launch_bounds__(512) void gather_kernel(const void* V, const int* order,
                                                     const int* offsets, const float* counts,
                                                     float* sums, float* gsum, const int* flag) {
    __shared__ float red[D];
    if (*flag) gather_body<true>(V, order, offsets, counts, sums, gsum, red);
    else       gather_body<false>(V, order, offsets, counts, sums, gsum, red);
}

// ------- Kernel 2: prototypes + protoW = proto @ W_r^T, emitted as bf16 in ---
// ------- MFMA B-fragment layout: pwB[((b>>3)*256 + col)*8 + (b&7)], b = k-dim ---
template<bool BH>
__device__ __forceinline__ void proto_body(const float* __restrict__ sums,
                                           const float* __restrict__ counts,
                                           const float* __restrict__ gsum,
                                           const void* __restrict__ W_r,
                                           unsigned short* __restrict__ pwB,
                                           float* __restrict__ proto) {
    const int b = blockIdx.x, t = threadIdx.x;
    float c = counts[b];
    proto[t] = (c > 0.5f) ? sums[b * D + t] / c : gsum[t] * (1.0f / N_ROWS);
    __syncthreads();
    // protoW[b][t] = sum_k proto[k] * W_r[t][k]
    float acc = 0.f;
    float w[8];
    #pragma unroll
    for (int c8 = 0; c8 < D / 8; ++c8) {
        ld8<BH>(W_r, (size_t)t * D + c8 * 8, w);
        #pragma unroll
        for (int j = 0; j < 8; ++j) acc = fmaf(proto[c8 * 8 + j], w[j], acc);
    }
    pwB[((size_t)(b >> 3) * 256 + t) * 8 + (b & 7)] = bf16r(acc);
}
__global__ __launch_bounds__(256) void proto_kernel(const float* sums, const float* counts,
                                                    const float* gsum, const void* W_r,
                                                    unsigned short* pwB, const int* flag) {
    __shared__ __align__(16) float proto[D];
    if (*flag) proto_body<true>(sums, counts, gsum, W_r, pwB, proto);
    else       proto_body<false>(sums, counts, gsum, W_r, pwB, proto);
}

// ------- Kernel 3: softmax+entropy -> bf16 MFMA matmul -> gated add -> LayerNorm -------
// (FROZEN: verbatim round-3 kernel, harness-verified at absmax 0.0156)
template<bool BH>
__device__ __forceinline__ void fused_body(const void* __restrict__ logits,
                                           const void* __restrict__ h_fused,
                                           const unsigned short* __restrict__ pwB,
                                           const void* __restrict__ gamma,
                                           const void* __restrict__ beta,
                                           void* __restrict__ out,
                                           float* __restrict__ smu,
                                           float* __restrict__ part1,
                                           float* __restrict__ part2,
                                           float* __restrict__ gate_lds) {
    const int t = threadIdx.x;
    const long long base_row = (long long)blockIdx.x * RT;

    // ---- phase 1: softmax + entropy for RT rows, 16 threads per row ----
    {
        const int grp = t >> 4, sub = t & 15;
        const long long row = base_row + grp;
        float x[32];
        #pragma unroll
        for (int c = 0; c < 4; ++c)
            ld8<BH>(logits, (size_t)row * B + sub * 32 + c * 8, &x[c * 8]);
        float m = x[0];
        #pragma unroll
        for (int k = 1; k < 32; ++k) m = fmaxf(m, x[k]);
        m = fmaxf(m, __shfl_xor(m, 1));
        m = fmaxf(m, __shfl_xor(m, 2));
        m = fmaxf(m, __shfl_xor(m, 4));
        m = fmaxf(m, __shfl_xor(m, 8));
        float S = 0.f;
        #pragma unroll
        for (int k = 0; k < 32; ++k) { x[k] = __expf(x[k] - m); S += x[k]; }
        S += __shfl_xor(S, 1); S += __shfl_xor(S, 2); S += __shfl_xor(S, 4); S += __shfl_xor(S, 8);
        const float inv = 1.0f / S;
        float ent = 0.f;
        #pragma unroll
        for (int k = 0; k < 32; ++k) {
            float p = x[k] * inv;
            ent = fmaf(p, __logf(p + 1e-9f), ent);   // sum p*log(p+1e-9) (negative)
            x[k] = p;
        }
        ent += __shfl_xor(ent, 1); ent += __shfl_xor(ent, 2);
        ent += __shfl_xor(ent, 4); ent += __shfl_xor(ent, 8);
        const float gate = -ent * 0.16035674514745464f;  // entropy / ln(512)
        // A-tile write: k = sub*32 + c*8 + j  ->  chunk kg = sub*4 + c, row = grp
        unsigned short* A16 = (unsigned short*)smu;
        #pragma unroll
        for (int c = 0; c < 4; ++c) {
            unsigned q0 = (unsigned)bf16r(x[c*8+0]) | ((unsigned)bf16r(x[c*8+1]) << 16);
            unsigned q1 = (unsigned)bf16r(x[c*8+2]) | ((unsigned)bf16r(x[c*8+3]) << 16);
            unsigned q2 = (unsigned)bf16r(x[c*8+4]) | ((unsigned)bf16r(x[c*8+5]) << 16);
            unsigned q3 = (unsigned)bf16r(x[c*8+6]) | ((unsigned)bf16r(x[c*8+7]) << 16);
            *(uint4*)&A16[((size_t)(sub * 4 + c) * 16 + grp) * 8] = make_uint4(q0, q1, q2, q3);
        }
        if (sub == 0) {
            gate_lds[grp] = gate;
            stf<BH>(out, (size_t)N_ROWS * D + row, 1.0f - gate);   // confidence
        }
    }
    __syncthreads();

    // ---- phase 2: residual[16][256] = P[16x512] @ PW[512x256] via bf16 MFMA ----
    {
        const int l  = t & 63, w = t >> 6;
        const int lr = l & 15, lg = l >> 4;
        f32x4 acc[4];
        const f32x4 fz = {0.f, 0.f, 0.f, 0.f};
        #pragma unroll
        for (int n = 0; n < 4; ++n) acc[n] = fz;
        const uint4* Ap = (const uint4*)smu;    // 16B chunk index = kg*16 + row
        const uint4* Bp = (const uint4*)pwB;    // 16B chunk index = kg*256 + col
        #pragma unroll 2
        for (int ks = 0; ks < 16; ++ks) {       // K = 32 per step
            const int kg = ks * 4 + lg;
            sh8 a = __builtin_bit_cast(sh8, Ap[kg * 16 + lr]);
            #pragma unroll
            for (int n = 0; n < 4; ++n) {
                sh8 b = __builtin_bit_cast(sh8, Bp[(size_t)kg * 256 + w * 64 + n * 16 + lr]);
                acc[n] = __builtin_amdgcn_mfma_f32_16x16x32_bf16(a, b, acc[n], 0, 0, 0);
            }
        }
        __syncthreads();                         // all waves done reading A -> reuse smu
        float* res = smu;                        // [16][RS]
        #pragma unroll
        for (int n = 0; n < 4; ++n)
            #pragma unroll
            for (int r = 0; r < 4; ++r)          // C/D: row = (l>>4)*4 + r, col = l&15
                res[(lg * 4 + r) * RS + (w * 64 + n * 16 + lr)] = acc[n][r];
    }
    __syncthreads();

    // ---- phase 3: gated add + LayerNorm ----
    {
        const float* res = smu;
        const float g  = ldf<BH>(gamma, t);
        const float bt = ldf<BH>(beta, t);
        const int wv = t >> 6, ln = t & 63;
        float hr[RT];
        #pragma unroll
        for (int r = 0; r < RT; ++r) {
            const long long row = base_row + r;
            float hv = fmaf(gate_lds[r], res[r * RS + t], ldf<BH>(h_fused, (size_t)row * D + t));
            hr[r] = hv;
            float s1 = hv, s2 = hv * hv;
            #pragma unroll
            for (int o = 32; o > 0; o >>= 1) { s1 += __shfl_xor(s1, o); s2 += __shfl_xor(s2, o); }
            if (ln == 0) { part1[r * 4 + wv] = s1; part2[r * 4 + wv] = s2; }
        }
        __syncthreads();
        #pragma unroll
        for (int r = 0; r < RT; ++r) {
            float sum = part1[r * 4 + 0] + part1[r * 4 + 1] + part1[r * 4 + 2] + part1[r * 4 + 3];
            float sq  = part2[r * 4 + 0] + part2[r * 4 + 1] + part2[r * 4 + 2] + part2[r * 4 + 3];
            float mean = sum * (1.0f / D);
            float var  = fmaf(-mean, mean, sq * (1.0f / D));
            float rstd = rsqrtf(var + 1e-5f);
            const long long row = base_row + r;
            stf<BH>(out, (size_t)row * D + t, fmaf((hr[r] - mean) * rstd, g, bt));
        }
    }
}
__global__ __launch_bounds__(256, 4) void fused_kernel(const void* logits, const void* h_fused,
                                                       const unsigned short* pwB, const void* gamma,
                                                       const void* beta, void* out, const int* flag) {
    __shared__ __align__(16) float sm[RT * RS + RT * 4 * 2 + RT];
    float* smu      = sm;
    float* part1    = sm + RT * RS;
    float* part2    = part1 + RT * 4;
    float* gate_lds = part2 + RT * 4;
    if (*flag) fused_body<true>(logits, h_fused, pwB, gamma, beta, out,
                                smu, part1, part2, gate_lds);
    else       fused_body<false>(logits, h_fused, pwB, gamma, beta, out,
                                 smu, part1, part2, gate_lds);
}

extern "C" void kernel_launch(void* const* d_in, const int* in_sizes, int n_in,
                              void* d_out, int out_size, void* d_ws, size_t ws_size,
                              hipStream_t stream) {
    const void* h_fused = d_in[0];
    const void* V       = d_in[1];
    const void* logits  = d_in[2];
    const void* bk      = d_in[3];
    const void* W_r     = d_in[4];
    const void* gamma   = d_in[5];
    const void* beta    = d_in[6];

    float* ws      = (float*)d_ws;
    float* sums    = ws;                                   // B*D = 131072 f32 (written exclusively by gather)
    float* counts  = ws + 131072;                          // B   = 512  (zeroed)
    float* gsum    = ws + 131584;                          // D   = 256  (zeroed)
    unsigned short* pwB = (unsigned short*)(ws + 131840);  // B*D bf16 = 262144 B (16B-aligned)
    int*   order   = (int*)(ws + 131840 + 65536);          // N_ROWS ints = 400000 B
    int*   offsets = order + N_ROWS;                       // B ints
    int*   cursor  = offsets + B;                          // B ints
    int*   flag    = cursor + B;                           // 1 int   (total ws ~1.19 MB)

    // only counts+gsum need zeroing now (sums/order/cursor are fully overwritten each call)
    hipMemsetAsync(counts, 0, (B + D) * sizeof(float), stream);
    sniff_kernel<<<1, 64, 0, stream>>>((const unsigned*)h_fused, flag);
    hist_kernel<<<256, 256, 0, stream>>>(bk, counts);
    scan_kernel<<<1, 512, 0, stream>>>(counts, offsets, cursor);
    scatter_kernel<<<256, 256, 0, stream>>>(bk, cursor, order);
    gather_kernel<<<B, 512, 0, stream>>>(V, order, offsets, counts, sums, gsum, flag);
    proto_kernel<<<B, 256, 0, stream>>>(sums, counts, gsum, W_r, pwB, flag);
    fused_kernel<<<N_ROWS / RT, 256, 0, stream>>>(logits, h_fused, pwB, gamma, beta, d_out, flag);
}